// Round 13
// baseline (422.166 us; speedup 1.0000x reference)
//
#include <hip/hip_runtime.h>
#include <cstdint>
#include <cstddef>

// GRU (reset_after) + dense(1)+sigmoid, masked by per-batch length t.
// R13 = R12 with ONE change: each gate's dot-product accumulation is split
// into INDEPENDENT partial accumulators (U-part: 4 accs x 8 dot2s, W-part:
// 3 accs x 4 dot2s) combined by a short f32 add tree. R12's single-acc
// chains were 44 serial dot2s x ~4cy dependency latency = ~176 cy/gate of
// pure latency (the dominant unexplained stall); fdot2 is opaque so the
// compiler cannot reassociate. Now 21 independent chains -> issue-bound.
// Structure unchanged: ONE WAVE per sequence (512 x 64), ZERO barriers,
// lane j owns gate columns {j,64+j,128+j} full-K, f16-pair weights in
// VGPRs via v_dot2_f32_f16, h state f16 in LDS (same-wave write->read),
// z/r weights pre-negated, c weights pre-doubled.

typedef float  v2f __attribute__((ext_vector_type(2)));
typedef float  v4f __attribute__((ext_vector_type(4)));
typedef _Float16 h2 __attribute__((ext_vector_type(2)));
typedef _Float16 h8 __attribute__((ext_vector_type(8)));

__device__ __forceinline__ float frcp(float x) { return __builtin_amdgcn_rcpf(x); }

#if defined(__has_builtin)
#if __has_builtin(__builtin_amdgcn_fdot2)
#define HAVE_FDOT2 1
#endif
#endif

__device__ __forceinline__ float fdot2(h2 a, h2 b, float acc) {
#ifdef HAVE_FDOT2
    return __builtin_amdgcn_fdot2(a, b, acc, false);
#else
    return fmaf((float)a.x, (float)b.x, fmaf((float)a.y, (float)b.y, acc));
#endif
}

#define PAIR(v8, m) __builtin_shufflevector((v8), (v8), 2*(m), 2*(m)+1)

// 4 dot2s against one h8 vector, all pair indices literal
#define DOT4(acc, Warr, off, v)                              \
    acc = fdot2((Warr)[(off) + 0], PAIR((v), 0), acc);       \
    acc = fdot2((Warr)[(off) + 1], PAIR((v), 1), acc);       \
    acc = fdot2((Warr)[(off) + 2], PAIR((v), 2), acc);       \
    acc = fdot2((Warr)[(off) + 3], PAIR((v), 3), acc);

__global__ __launch_bounds__(64, 1) void gru1_kernel(
    const float* __restrict__ xg,      // (512,1024,24)
    const int*   __restrict__ tg,      // (512,)
    const float* __restrict__ Wg,      // (24,192)
    const float* __restrict__ Ug,      // (64,192)
    const float* __restrict__ bg,      // (2,192)
    const float* __restrict__ Wdg,     // (64,1)
    const float* __restrict__ bdg,     // (1,)
    float*       __restrict__ outg)    // (512,1024)
{
    const int b = blockIdx.x;
    const int j = threadIdx.x;          // lane 0..63

    __shared__ __align__(16) _Float16 h16[64];          // f16 state, 128 B
    __shared__ __align__(16) _Float16 xbuf[64 * 24];    // chunk of x, f16
    __shared__ __align__(16) float    p_lds[64 * 66];   // [step][lane], pad 66
    __shared__ float o_last;

    const int   t    = tg[b];
    float*      outb = outg + (size_t)b * 1024;
    const float bdv  = bdg[0];

    if (t <= 0) {
        const float fill = frcp(1.f + __expf(-bdv));
        for (int i = j; i < 1024; i += 64) outb[i] = fill;
        return;
    }

    // ---- weight preload: f16 pairs along K; z/r negated, c doubled ----
    h2 Uz[32], Ur[32], Uc[32];
    #pragma unroll
    for (int k = 0; k < 32; ++k) {
        const float* r0 = Ug + (2 * k)     * 192;
        const float* r1 = Ug + (2 * k + 1) * 192;
        Uz[k] = (h2){ (_Float16)(-r0[j]),            (_Float16)(-r1[j]) };
        Ur[k] = (h2){ (_Float16)(-r0[64 + j]),       (_Float16)(-r1[64 + j]) };
        Uc[k] = (h2){ (_Float16)(2.f * r0[128 + j]), (_Float16)(2.f * r1[128 + j]) };
    }
    h2 Wz[12], Wr[12], Wc[12];
    #pragma unroll
    for (int d = 0; d < 12; ++d) {
        const float* r0 = Wg + (2 * d)     * 192;
        const float* r1 = Wg + (2 * d + 1) * 192;
        Wz[d] = (h2){ (_Float16)(-r0[j]),            (_Float16)(-r1[j]) };
        Wr[d] = (h2){ (_Float16)(-r0[64 + j]),       (_Float16)(-r1[64 + j]) };
        Wc[d] = (h2){ (_Float16)(2.f * r0[128 + j]), (_Float16)(2.f * r1[128 + j]) };
    }
    const float bzn  = -(bg[j]      + bg[192 + j]);     // z: negated
    const float brn  = -(bg[64 + j] + bg[256 + j]);     // r: negated
    const float b0c2 = 2.f * bg[128 + j];               // c: doubled
    const float b1c2 = 2.f * bg[320 + j];
    const float wdj  = Wdg[j];

    const float* xb = xg + (size_t)b * 24576;   // 1024*24

    // ---- stage chunk 0: lane j handles x row j (24 f32 -> 24 f16) ----
    {
        const v4f* src = (const v4f*)(xb + j * 24);
        v4f g0 = src[0], g1 = src[1], g2 = src[2], g3 = src[3], g4 = src[4], g5 = src[5];
        h8 o0, o1, o2;
        #pragma unroll
        for (int i = 0; i < 4; ++i) {
            o0[i]     = (_Float16)g0[i];  o0[4 + i] = (_Float16)g1[i];
            o1[i]     = (_Float16)g2[i];  o1[4 + i] = (_Float16)g3[i];
            o2[i]     = (_Float16)g4[i];  o2[4 + i] = (_Float16)g5[i];
        }
        h8* dst = (h8*)(xbuf + j * 24);
        dst[0] = o0; dst[1] = o1; dst[2] = o2;
    }
    h16[j] = (_Float16)0.f;

    // prefetch chunk 1 (f32, converted at commit)
    v4f pf[6];
    if (t > 64) {
        const v4f* ns = (const v4f*)(xb + 1536 + j * 24);
        #pragma unroll
        for (int i = 0; i < 6; ++i) pf[i] = ns[i];
    }

    float hold = 0.f;   // lane j's own h_j (f32, full precision)

    for (int base = 0; base < t; base += 64) {
        const int cnt = (t - base < 64) ? (t - base) : 64;

        if (base > 0) {
            // previous chunk done. Reduce its outputs (before p_lds reuse),
            // commit prefetched x, prefetch next. Same-wave ordering only.
            {
                const v2f* pr = (const v2f*)(p_lds + j * 66);
                v2f s2 = (v2f){0.f, 0.f};
                #pragma unroll
                for (int i = 0; i < 32; ++i) s2 += pr[i];
                outb[base - 64 + j] = frcp(1.f + __expf(-(s2.x + s2.y + bdv)));
            }
            {
                h8 o0, o1, o2;
                #pragma unroll
                for (int i = 0; i < 4; ++i) {
                    o0[i]     = (_Float16)pf[0][i];  o0[4 + i] = (_Float16)pf[1][i];
                    o1[i]     = (_Float16)pf[2][i];  o1[4 + i] = (_Float16)pf[3][i];
                    o2[i]     = (_Float16)pf[4][i];  o2[4 + i] = (_Float16)pf[5][i];
                }
                h8* dst = (h8*)(xbuf + j * 24);
                dst[0] = o0; dst[1] = o1; dst[2] = o2;
            }
            if (base + 64 < t) {
                const v4f* ns = (const v4f*)(xb + (size_t)(base + 64) * 24 + j * 24);
                #pragma unroll
                for (int i = 0; i < 6; ++i) pf[i] = ns[i];
            }
        }

        for (int c = 0; c < cnt; ++c) {
            // ---- issue ALL LDS reads up front: h first, then x row c ----
            const h8* hp = (const h8*)h16;
            h8 hv[8];
            #pragma unroll
            for (int i = 0; i < 8; ++i) hv[i] = hp[i];
            const h8* xp = (const h8*)(xbuf + c * 24);
            h8 xa = xp[0], xcv = xp[1], xe = xp[2];

            // ---- x-part (W-dots) first, 3 independent accs per gate ----
            float rw0 = brn, rw1 = 0.f, rw2 = 0.f;
            DOT4(rw0, Wr, 0, xa); DOT4(rw1, Wr, 4, xcv); DOT4(rw2, Wr, 8, xe);
            float zw0 = bzn, zw1 = 0.f, zw2 = 0.f;
            DOT4(zw0, Wz, 0, xa); DOT4(zw1, Wz, 4, xcv); DOT4(zw2, Wz, 8, xe);
            float cw0 = b0c2, cw1 = 0.f, cw2 = 0.f;
            DOT4(cw0, Wc, 0, xa); DOT4(cw1, Wc, 4, xcv); DOT4(cw2, Wc, 8, xe);

            // ---- h-part (U-dots): 4 independent accs per gate; r first ----
            float ru0 = 0.f, ru1 = 0.f, ru2 = 0.f, ru3 = 0.f;
            DOT4(ru0, Ur,  0, hv[0]); DOT4(ru0, Ur,  4, hv[1]);
            DOT4(ru1, Ur,  8, hv[2]); DOT4(ru1, Ur, 12, hv[3]);
            DOT4(ru2, Ur, 16, hv[4]); DOT4(ru2, Ur, 20, hv[5]);
            DOT4(ru3, Ur, 24, hv[6]); DOT4(ru3, Ur, 28, hv[7]);
            const float ran = ((ru0 + ru1) + (ru2 + ru3)) + ((rw0 + rw1) + rw2);
            const float er  = __expf(ran);       // cooks under z/c dots

            float zu0 = 0.f, zu1 = 0.f, zu2 = 0.f, zu3 = 0.f;
            DOT4(zu0, Uz,  0, hv[0]); DOT4(zu0, Uz,  4, hv[1]);
            DOT4(zu1, Uz,  8, hv[2]); DOT4(zu1, Uz, 12, hv[3]);
            DOT4(zu2, Uz, 16, hv[4]); DOT4(zu2, Uz, 20, hv[5]);
            DOT4(zu3, Uz, 24, hv[6]); DOT4(zu3, Uz, 28, hv[7]);
            const float zan = ((zu0 + zu1) + (zu2 + zu3)) + ((zw0 + zw1) + zw2);
            const float ez  = __expf(zan);       // cooks under c dots

            float cu0 = b1c2, cu1 = 0.f, cu2 = 0.f, cu3 = 0.f;
            DOT4(cu0, Uc,  0, hv[0]); DOT4(cu0, Uc,  4, hv[1]);
            DOT4(cu1, Uc,  8, hv[2]); DOT4(cu1, Uc, 12, hv[3]);
            DOT4(cu2, Uc, 16, hv[4]); DOT4(cu2, Uc, 20, hv[5]);
            DOT4(cu3, Uc, 24, hv[6]); DOT4(cu3, Uc, 28, hv[7]);
            const float ca  = (cu0 + cu1) + (cu2 + cu3);          // 2*(hc+b1c)
            const float xca = (cw0 + cw1) + cw2;                  // 2*(xc+b0c)

            const float r  = frcp(1.f + er);
            const float z  = frcp(1.f + ez);
            const float y  = fmaf(r, ca, xca);                 // 2*(xc + r*hc)
            const float cg = 1.f - 2.f * frcp(1.f + __expf(y));
            const float hn = fmaf(z, hold - cg, cg);           // z*h + (1-z)*c
            hold = hn;

            h16[j] = (_Float16)hn;          // next step's state (ds_write_b16)
            p_lds[c * 66 + j] = hn * wdj;   // output partial
        }
    }

    // ---- final (possibly partial) chunk reduce ----
    const int lastbase = ((t - 1) >> 6) << 6;
    const int lastcnt  = t - lastbase;
    if (j < lastcnt) {
        const v2f* pr = (const v2f*)(p_lds + j * 66);
        v2f s2 = (v2f){0.f, 0.f};
        #pragma unroll
        for (int i = 0; i < 32; ++i) s2 += pr[i];
        const float o = frcp(1.f + __expf(-(s2.x + s2.y + bdv)));
        outb[lastbase + j] = o;
        if (j == lastcnt - 1) o_last = o;
    }
    // ---- constant tail fill (same-wave visibility; R3-proven pattern) ----
    const float fill = o_last;
    for (int i = t + j; i < 1024; i += 64) outb[i] = fill;
}

extern "C" void kernel_launch(void* const* d_in, const int* in_sizes, int n_in,
                              void* d_out, int out_size, void* d_ws, size_t ws_size,
                              hipStream_t stream) {
    (void)in_sizes; (void)n_in; (void)d_ws; (void)ws_size; (void)out_size;
    const float* x  = (const float*)d_in[0];
    const int*   t  = (const int*)d_in[1];
    const float* W  = (const float*)d_in[2];
    const float* U  = (const float*)d_in[3];
    const float* bb = (const float*)d_in[4];
    const float* Wd = (const float*)d_in[5];
    const float* bd = (const float*)d_in[6];
    float* out = (float*)d_out;

    hipLaunchKernelGGL(gru1_kernel, dim3(512), dim3(64), 0, stream,
                       x, t, W, U, bb, Wd, bd, out);
}